// Round 4
// baseline (438.071 us; speedup 1.0000x reference)
//
#include <hip/hip_runtime.h>
#include <math.h>

#define NROWS 200000
#define C 384
#define G 383
#define M 384          // G + 1
#define EPS 1e-5f
#define SQRTC 19.595917942265423f   // sqrt(384)

#define NBLK1 1024
#define THR1 512                    // 8 waves/block; 1024 blocks = 4/CU = 32 waves/CU
#define NWAVES ((NBLK1 * THR1) / 64)   // 8192
#define NPAIRS (NROWS / 2)          // 100000 row pairs
#define NBLK4 576                   // triple-sum blocks (M*M/256)

// ---------------- workspace layout (floats) ----------------
// Transposed partials: part[j*NBLK1 + blk], j in [0,1152):
//   j in [0,384)    = cnt for group j
//   j in [384,768)  = sum for group j-384
//   j in [768,1152) = sumsq for group j-768
#define WS_PART  0
#define WS_PROTO (1152 * NBLK1)
#define WS_STD   (WS_PROTO + 384)
#define WS_P3    (WS_STD + 384)

// K1: one wave per ROW PAIR. 3 full-wave float4 loads cover 192 chunks (2 rows).
// Register shuffle-reduce; 6 LDS atomics per pair (lane 0); transposed flush.
__global__ __launch_bounds__(THR1) void stats_kernel(const float4* __restrict__ pred4,
                                                     const int* __restrict__ tgt,
                                                     float* __restrict__ ws,
                                                     int n_pairs) {
    __shared__ float l[1152];       // [cnt|sum|ss] x 384
    const int tid = threadIdx.x;
    for (int i = tid; i < 1152; i += THR1) l[i] = 0.f;
    __syncthreads();

    const int lane = tid & 63;
    const int wv   = (blockIdx.x * THR1 + tid) >> 6;

    for (int p = wv; p < n_pairs; p += NWAVES) {
        const float4* rp = pred4 + (size_t)p * 192;   // 2 rows = 192 float4 chunks
        float4 v0 = rp[lane];          // chunks   0..63  -> row A
        float4 v1 = rp[64 + lane];     // chunks  64..127 -> lanes<32: row A, lanes>=32: row B
        float4 v2 = rp[128 + lane];    // chunks 128..191 -> row B

        float s1 = (v1.x + v1.y) + (v1.z + v1.w);
        float q1 = fmaf(v1.x, v1.x, fmaf(v1.y, v1.y, fmaf(v1.z, v1.z, v1.w * v1.w)));
        bool lowhalf = (lane < 32);

        float sA = (v0.x + v0.y) + (v0.z + v0.w) + (lowhalf ? s1 : 0.f);
        float qA = fmaf(v0.x, v0.x, fmaf(v0.y, v0.y, fmaf(v0.z, v0.z, v0.w * v0.w)))
                 + (lowhalf ? q1 : 0.f);
        float sB = (v2.x + v2.y) + (v2.z + v2.w) + (lowhalf ? 0.f : s1);
        float qB = fmaf(v2.x, v2.x, fmaf(v2.y, v2.y, fmaf(v2.z, v2.z, v2.w * v2.w)))
                 + (lowhalf ? 0.f : q1);

#pragma unroll
        for (int off = 32; off > 0; off >>= 1) {
            sA += __shfl_down(sA, off);
            qA += __shfl_down(qA, off);
            sB += __shfl_down(sB, off);
            qB += __shfl_down(qB, off);
        }
        if (lane == 0) {
            int segA = tgt[2 * p];
            int segB = tgt[2 * p + 1];
            atomicAdd(&l[segA], 1.0f);
            atomicAdd(&l[384 + segA], sA);
            atomicAdd(&l[768 + segA], qA);
            atomicAdd(&l[segB], 1.0f);
            atomicAdd(&l[384 + segB], sB);
            atomicAdd(&l[768 + segB], qB);
        }
    }
    __syncthreads();

    // transposed flush: column blk of row j
    const int blk = blockIdx.x;
    for (int i = tid; i < 1152; i += THR1)
        ws[WS_PART + (size_t)i * NBLK1 + blk] = l[i];
}

// K2: fused reduce+finalize. Block g reduces three contiguous 1024-float rows
// (float4 loads), computes mean/std for group g, writes proto[g]/std[g].
__global__ __launch_bounds__(256) void finalize_kernel(float* __restrict__ ws) {
    __shared__ float wred[4][3];
    const int g   = blockIdx.x;         // [0, 384)
    const int tid = threadIdx.x;        // 256 threads; 4 floats each per row

    const float4* cnt_row = (const float4*)(ws + WS_PART + (size_t)g * NBLK1);
    const float4* sum_row = (const float4*)(ws + WS_PART + (size_t)(384 + g) * NBLK1);
    const float4* ss_row  = (const float4*)(ws + WS_PART + (size_t)(768 + g) * NBLK1);

    float4 c4 = cnt_row[tid], s4 = sum_row[tid], q4 = ss_row[tid];
    float c = (c4.x + c4.y) + (c4.z + c4.w);
    float s = (s4.x + s4.y) + (s4.z + s4.w);
    float q = (q4.x + q4.y) + (q4.z + q4.w);

#pragma unroll
    for (int off = 32; off > 0; off >>= 1) {
        c += __shfl_down(c, off);
        s += __shfl_down(s, off);
        q += __shfl_down(q, off);
    }
    if ((tid & 63) == 0) {
        wred[tid >> 6][0] = c;
        wred[tid >> 6][1] = s;
        wred[tid >> 6][2] = q;
    }
    __syncthreads();
    if (tid == 0) {
        float cnt_r = wred[0][0] + wred[1][0] + wred[2][0] + wred[3][0];
        float sum   = wred[0][1] + wred[1][1] + wred[2][1] + wred[3][1];
        float ss    = wred[0][2] + wred[1][2] + wred[2][2] + wred[3][2];
        float mean = 0.f, sd = 0.f;
        if (g < G && cnt_r > 0.5f) {
            float cnt = cnt_r * (float)C;
            mean = sum / cnt;
            if (cnt_r > 1.5f) {
                float cs    = ss - cnt * mean * mean;
                float denom = fmaxf(cnt - 1.0f, 1.0f);
                sd = sqrtf(fmaxf(cs / denom, 0.f));
            }
        }
        ws[WS_PROTO + g] = mean;
        ws[WS_STD + g]   = sd;
    }
}

// K3: one thread per (x,a); sum over b>a of s/(norm_ab + s + EPS); per-block partial.
__global__ void triple_sum_kernel(const float* __restrict__ ws,
                                  float* __restrict__ part3) {
    __shared__ float sp[M];
    __shared__ float sst[M];
    __shared__ float wsum[4];
    const int tid = threadIdx.x;

    for (int i = tid; i < M; i += blockDim.x) {
        sp[i]  = ws[WS_PROTO + i];
        sst[i] = ws[WS_STD + i];
    }
    __syncthreads();

    const int idx = blockIdx.x * blockDim.x + tid;   // idx = x*M + a
    float partial = 0.f;
    {
        const int x = idx / M;
        const int a = idx - x * M;
        const float pa = sp[a];
        const float u  = fabsf(pa - sp[x]);
        const float t  = u / (u * SQRTC + EPS);      // |d[x,a]|
        if (t > 0.f) {
            const float sa = sst[a];
#pragma unroll 4
            for (int b = a + 1; b < M; ++b) {
                float nab = fabsf(sp[b] - pa) * SQRTC;
                float s   = t * (sa + sst[b]);
                partial += s * __builtin_amdgcn_rcpf(nab + s + EPS);
            }
        }
    }

#pragma unroll
    for (int off = 32; off > 0; off >>= 1)
        partial += __shfl_down(partial, off);
    if ((tid & 63) == 0) wsum[tid >> 6] = partial;
    __syncthreads();
    if (tid == 0)
        part3[blockIdx.x] = wsum[0] + wsum[1] + wsum[2] + wsum[3];
}

// K4: reduce 576 block partials, scale, write scalar out.
__global__ void write_out_kernel(const float* __restrict__ part3,
                                 float* __restrict__ out) {
    __shared__ float wsum[9];
    const int tid = threadIdx.x;        // blockDim.x == 576
    float v = part3[tid];
#pragma unroll
    for (int off = 32; off > 0; off >>= 1)
        v += __shfl_down(v, off);
    if ((tid & 63) == 0) wsum[tid >> 6] = v;
    __syncthreads();
    if (tid == 0) {
        float acc = 0.f;
#pragma unroll
        for (int w = 0; w < 9; ++w) acc += wsum[w];
        out[0] = acc / ((float)M * (float)M * (float)M);
    }
}

extern "C" void kernel_launch(void* const* d_in, const int* in_sizes, int n_in,
                              void* d_out, int out_size, void* d_ws, size_t ws_size,
                              hipStream_t stream) {
    const float4* pred4 = (const float4*)d_in[0];
    const int*    tgt   = (const int*)d_in[1];
    float* ws  = (float*)d_ws;
    float* out = (float*)d_out;

    stats_kernel<<<NBLK1, THR1, 0, stream>>>(pred4, tgt, ws, NPAIRS);
    finalize_kernel<<<384, 256, 0, stream>>>(ws);
    triple_sum_kernel<<<NBLK4, 256, 0, stream>>>(ws, ws + WS_P3);
    write_out_kernel<<<1, 576, 0, stream>>>(ws + WS_P3, out);
}